// Round 4
// baseline (1100.739 us; speedup 1.0000x reference)
//
#include <hip/hip_runtime.h>

// Reference constants
constexpr int   TH    = 8;     // TREE_HEIGHT
constexpr int   NNEG  = 8;     // N_NEG
constexpr int   HID4  = 256;   // HIDDEN in float4 units (1024/4)
constexpr int   FOLD4 = 128;   // folded row (512 floats) in float4 units
constexpr int   CAP   = 32;    // max refs per node row (Poisson(0.74); P(>=32)~1e-40)
constexpr float SCR_F = 6.2831853071795864769f; // 2*pi

// ---------------------------------------------------------------------------
// Pass 0: zero the per-row cursors (ws is poisoned every iteration).
// ---------------------------------------------------------------------------
__global__ __launch_bounds__(256)
void cursor_zero(int* __restrict__ cursor, int n)
{
    for (int i = blockIdx.x * 256 + threadIdx.x; i < n; i += gridDim.x * 256)
        cursor[i] = 0;
}

// ---------------------------------------------------------------------------
// Pass 1: build inverted index row -> list of dest chunks referencing it.
// Ref e in [0, 16384)        : p2 ref   (b=e>>3, h=e&7), chunk = 131072 + e
// Ref e in [16384, 147456)   : neg ref  (linear [b][n][h]), chunk = e - 16384
// Fixed-capacity buckets (CAP=32) eliminate the prefix-scan; bucket ORDER is
// nondeterministic but each entry triggers an identical 2KB copy to a unique
// chunk, so the final dest contents are deterministic.
// ---------------------------------------------------------------------------
__global__ __launch_bounds__(256)
void idx_fill(const int* __restrict__ pos_path,
              const int* __restrict__ neg_path,
              int* __restrict__ cursor,
              int* __restrict__ entries,
              int batch)
{
    const int e   = blockIdx.x * 256 + threadIdx.x;
    const int np2 = batch * TH;                  // 16384
    const int tot = np2 + batch * NNEG * TH;     // 147456
    if (e >= tot) return;
    int row, chunk;
    if (e < np2) {
        const int b = e >> 3, h = e & 7;
        row   = pos_path[b * 2 * TH + TH + h];   // p2[b][h]
        chunk = batch * NNEG * TH + e;           // p2 chunks after neg chunks
    } else {
        const int en = e - np2;
        row   = neg_path[en];
        chunk = en;
    }
    const int j = atomicAdd(&cursor[row], 1);
    if (j < CAP) entries[(row << 5) + j] = chunk;
}

// ---------------------------------------------------------------------------
// Pass 2: PUSH. Sweep emb rows in ascending order (sparse streaming read),
// fold lo+hi in registers, scatter one 2KB folded copy per referencing chunk.
// Reads have a fully sequential front (latency-friendly); writes are
// fire-and-forget 2KB contiguous chunks. One wave per row, grid-stride.
// ---------------------------------------------------------------------------
__global__ __launch_bounds__(256)
void push_kernel(const float* __restrict__ emb,
                 const int*   __restrict__ cursor,
                 const int*   __restrict__ entries,
                 float*       __restrict__ dest,
                 int n_nodes)
{
    const int lane = threadIdx.x & 63;
    const int wave = blockIdx.x * 4 + (threadIdx.x >> 6);
    const int nw   = gridDim.x * 4;

    const float4* __restrict__ embv = (const float4*)emb;
    float4* __restrict__ dv = (float4*)dest;

    for (int r = wave; r < n_nodes; r += nw) {
        const int c = cursor[r];
        if (c == 0) continue;
        const float4* row = embv + (long)r * HID4;
        const float4 a0 = row[lane];         // lo half cols [0,256)
        const float4 a1 = row[64 + lane];    // lo half cols [256,512)
        const float4 a2 = row[128 + lane];   // hi half
        const float4 a3 = row[192 + lane];   // hi half
        float4 o0, o1;
        o0.x = a0.x + a2.x; o0.y = a0.y + a2.y;
        o0.z = a0.z + a2.z; o0.w = a0.w + a2.w;
        o1.x = a1.x + a3.x; o1.y = a1.y + a3.y;
        o1.z = a1.z + a3.z; o1.w = a1.w + a3.w;
        const int cc = (c < CAP) ? c : CAP;
        for (int k = 0; k < cc; ++k) {
            const int chunk = entries[(r << 5) + k];
            float4* d = dv + (long)chunk * FOLD4;
            d[lane]      = o0;
            d[64 + lane] = o1;
        }
    }
}

// ---------------------------------------------------------------------------
// Pass 3: per-batch prep from the p2 dest chunks (fully sequential reads).
//   sp2[b][512] = sum_h dest_p2[b][h]   (h-order, bit-identical to before)
//   C[b][n]     = (diff_pos - 1 - (raw_n==0)) * 2pi
// ---------------------------------------------------------------------------
__global__ __launch_bounds__(64)
void sp2_kernel(const float* __restrict__ dest,
                const int*   __restrict__ pos_path,
                const int*   __restrict__ neg_path,
                float*       __restrict__ sp2_out,   // [BATCH][512]
                float*       __restrict__ C_out,     // [BATCH][NNEG]
                int batch)
{
    const int b = blockIdx.x;
    const int l = threadIdx.x;          // 0..63

    if (l < NNEG) {
        int p1v[TH], p2v[TH];
#pragma unroll
        for (int i = 0; i < TH; i++) {
            p1v[i] = pos_path[b * 2 * TH + i];
            p2v[i] = pos_path[b * 2 * TH + TH + i];
        }
        int inter_pos = 0;
#pragma unroll
        for (int i = 0; i < TH; i++) {
            bool f = false;
#pragma unroll
            for (int j = 0; j < TH; j++) f = f || (p1v[i] == p2v[j]);
            inter_pos += f ? 1 : 0;
        }
        const float diff_pos = fmaxf((float)(TH - inter_pos), 1.0f);

        const int n = l;
        int negj[TH];
#pragma unroll
        for (int j = 0; j < TH; j++)
            negj[j] = neg_path[(b * NNEG + n) * TH + j];

        int inter_n = 0;
#pragma unroll
        for (int i = 0; i < TH; i++) {
            bool f = false;
#pragma unroll
            for (int j = 0; j < TH; j++) f = f || (p1v[i] == negj[j]);
            inter_n += f ? 1 : 0;
        }
        const int raw = TH - inter_n;   // diff_neg_raw (integer, >= 0)
        C_out[b * NNEG + n] = (diff_pos - 1.0f - (raw == 0 ? 1.0f : 0.0f)) * SCR_F;
    }

    // p2 chunks live at [batch*NNEG*TH + b*TH .. +TH)
    const float4* __restrict__ dv =
        (const float4*)dest + (long)(batch * NNEG * TH + b * TH) * FOLD4;
    float4 s0 = {0.f, 0.f, 0.f, 0.f};
    float4 s1 = {0.f, 0.f, 0.f, 0.f};
#pragma unroll
    for (int h = 0; h < TH; h++) {
        const float4 f0 = dv[h * FOLD4 + l];
        const float4 f1 = dv[h * FOLD4 + 64 + l];
        s0.x += f0.x; s0.y += f0.y; s0.z += f0.z; s0.w += f0.w;
        s1.x += f1.x; s1.y += f1.y; s1.z += f1.z; s1.w += f1.w;
    }
    float4* sp2v = (float4*)sp2_out;
    sp2v[(long)b * FOLD4 + l]      = s0;
    sp2v[(long)b * FOLD4 + 64 + l] = s1;
}

// ---------------------------------------------------------------------------
// Pass 4: one wave per (b,n) slot; reads its 8 chunks FULLY SEQUENTIALLY
// (16KB contiguous), sums in h-order, relu^2, butterfly, sqrt -> partial.
// ---------------------------------------------------------------------------
__global__ __launch_bounds__(64)
void neg2_kernel(const float* __restrict__ dest,
                 const float* __restrict__ sp2_in,    // [BATCH][512]
                 const float* __restrict__ C_in,      // [BATCH*NNEG]
                 float*       __restrict__ partial)   // [BATCH*NNEG]
{
    const int s = blockIdx.x;           // slot = b*NNEG + n
    const int l = threadIdx.x;          // 0..63
    const int b = s >> 3;

    const float4* __restrict__ dv = (const float4*)dest + (long)s * TH * FOLD4;
    float4 s0 = {0.f, 0.f, 0.f, 0.f};
    float4 s1 = {0.f, 0.f, 0.f, 0.f};
#pragma unroll
    for (int h = 0; h < TH; h++) {
        const float4 f0 = dv[h * FOLD4 + l];
        const float4 f1 = dv[h * FOLD4 + 64 + l];
        s0.x += f0.x; s0.y += f0.y; s0.z += f0.z; s0.w += f0.w;
        s1.x += f1.x; s1.y += f1.y; s1.z += f1.z; s1.w += f1.w;
    }

    const float4* sp2v = (const float4*)sp2_in;
    const float4 p0 = sp2v[(long)b * FOLD4 + l];
    const float4 p1 = sp2v[(long)b * FOLD4 + 64 + l];
    const float c = C_in[s];

    float v, a = 0.f;
    v = c + 0.5f * (s0.x - p0.x); v = fmaxf(v, 0.f); a += v * v;
    v = c + 0.5f * (s0.y - p0.y); v = fmaxf(v, 0.f); a += v * v;
    v = c + 0.5f * (s0.z - p0.z); v = fmaxf(v, 0.f); a += v * v;
    v = c + 0.5f * (s0.w - p0.w); v = fmaxf(v, 0.f); a += v * v;
    v = c + 0.5f * (s1.x - p1.x); v = fmaxf(v, 0.f); a += v * v;
    v = c + 0.5f * (s1.y - p1.y); v = fmaxf(v, 0.f); a += v * v;
    v = c + 0.5f * (s1.z - p1.z); v = fmaxf(v, 0.f); a += v * v;
    v = c + 0.5f * (s1.w - p1.w); v = fmaxf(v, 0.f); a += v * v;

#pragma unroll
    for (int off = 32; off > 0; off >>= 1) {
        a += __shfl_down(a, off, 64);
    }
    if (l == 0) partial[s] = sqrtf(a);
}

// ---------------------------------------------------------------------------
// Pass 5: single-block final reduction of the 16384 partials -> out[0].
// ---------------------------------------------------------------------------
__global__ __launch_bounds__(1024)
void reduce_kernel(const float* __restrict__ partial, int nval,
                   float* __restrict__ out)
{
    const int t = threadIdx.x;
    float s = 0.f;
    for (int i = t; i < nval; i += 1024) s += partial[i];

#pragma unroll
    for (int off = 32; off > 0; off >>= 1) {
        s += __shfl_down(s, off, 64);
    }
    __shared__ float s_red[16];
    const int lane = t & 63;
    const int wid  = t >> 6;
    if (lane == 0) s_red[wid] = s;
    __syncthreads();
    if (t == 0) {
        float tot = 0.f;
#pragma unroll
        for (int w = 0; w < 16; w++) tot += s_red[w];
        out[0] = tot;
    }
}

extern "C" void kernel_launch(void* const* d_in, const int* in_sizes, int n_in,
                              void* d_out, int out_size, void* d_ws, size_t ws_size,
                              hipStream_t stream) {
    const float* emb      = (const float*)d_in[0];
    const int*   pos_path = (const int*)d_in[1];
    const int*   neg_path = (const int*)d_in[2];
    float*       out      = (float*)d_out;

    const int BATCH    = in_sizes[1] / (2 * TH);   // 2048
    const int N_NODES  = in_sizes[0] / 1024;       // 200000
    const int N_CHUNKS = BATCH * (NNEG * TH + TH); // 147456 (neg then p2)
    const int N_REFS   = N_CHUNKS;                 // one ref per chunk

    // Workspace layout (~330 MB; ws >= 3 GB)
    float* dest    = (float*)d_ws;                          // N_CHUNKS*512 f32
    float* sp2     = dest + (size_t)N_CHUNKS * 512;         // BATCH*512 f32
    float* Cb      = sp2 + (size_t)BATCH * 512;             // BATCH*NNEG f32
    float* partial = Cb  + (size_t)BATCH * NNEG;            // BATCH*NNEG f32
    int*   cursor  = (int*)(partial + (size_t)BATCH * NNEG);// N_NODES int
    int*   entries = cursor + N_NODES;                      // N_NODES*CAP int

    cursor_zero<<<512, 256, 0, stream>>>(cursor, N_NODES);
    idx_fill<<<(N_REFS + 255) / 256, 256, 0, stream>>>(pos_path, neg_path,
                                                       cursor, entries, BATCH);
    push_kernel<<<4096, 256, 0, stream>>>(emb, cursor, entries, dest, N_NODES);
    sp2_kernel<<<BATCH, 64, 0, stream>>>(dest, pos_path, neg_path, sp2, Cb,
                                         BATCH);
    neg2_kernel<<<BATCH * NNEG, 64, 0, stream>>>(dest, sp2, Cb, partial);
    reduce_kernel<<<1, 1024, 0, stream>>>(partial, BATCH * NNEG, out);
}